// Round 6
// baseline (767.473 us; speedup 1.0000x reference)
//
#include <hip/hip_runtime.h>
#include <hip/hip_bf16.h>

// Fully-fused MLP: featurize + (GEMM+LN+tanh) x3 + final dot, one kernel.
// R6: 32x32x16 MFMA (same 64x64 wave tile; acc 64 AGPR unchanged, frees
// ~24 VGPRs vs 16x16x32) + depth-4 rolling B prefetch funded by those regs.
// R5 showed ~45% stall inside GEMM with depth-1 prefetch at the exact
// 128-reg/wave occupancy boundary.

typedef __attribute__((ext_vector_type(8))) short bf16x8;    // 8 bf16
typedef __attribute__((ext_vector_type(16))) float f32x16;   // 32x32 acc

#define LN_EPS 1e-5f

__device__ __forceinline__ float bf2f(short u) {
  union { unsigned u; float f; } c;
  c.u = ((unsigned)(unsigned short)u) << 16;
  return c.f;
}
// RNE float->bf16
__device__ __forceinline__ unsigned short f2bf(float f) {
  union { float f; unsigned u; } c; c.f = f;
  unsigned u = c.u;
  u += 0x7FFFu + ((u >> 16) & 1u);
  return (unsigned short)(u >> 16);
}
// tanh(x) = 1 - 2/(1+e^{2x}); v_exp_f32 + v_rcp_f32, ~1e-7 rel err.
__device__ __forceinline__ float fast_tanh(float x) {
  float e = __builtin_amdgcn_exp2f(x * 2.8853900817779268f);  // 2*log2(e)
  float r = __builtin_amdgcn_rcpf(e + 1.0f);
  return 1.0f - 2.0f * r;
}

// ------------------------------------------------------------- pack weights
// 32x32x16 B-fragment order: P[((c*S + s)*2 + g)*512 + lane*8 + j] =
//   W[c*64 + g*32 + (lane&31)][s*16 + (lane>>5)*8 + j]
// -> per (c,s,g) one contiguous 1KB chunk in exact lane order.
// Wave id: <576 -> W0 (16 c x 36 s), <1600 -> W1 (16x64), else W2 (8x64).
__global__ void pack_all(const float* __restrict__ W0,
                         const float* __restrict__ W1,
                         const float* __restrict__ W2,
                         unsigned short* __restrict__ P0,
                         unsigned short* __restrict__ P1,
                         unsigned short* __restrict__ P2) {
  const int wv = blockIdx.x * 4 + (threadIdx.x >> 6);
  const int lane = threadIdx.x & 63;
  const float* W; unsigned short* P; int K, S, cs;
  if (wv < 576)       { W = W0; P = P0; K = 576;  S = 36; cs = wv; }
  else if (wv < 1600) { W = W1; P = P1; K = 1024; S = 64; cs = wv - 576; }
  else                { W = W2; P = P2; K = 1024; S = 64; cs = wv - 1600; }
  const int s = cs % S, c = cs / S;
  const int l31 = lane & 31, kg = lane >> 5;
#pragma unroll
  for (int g = 0; g < 2; ++g) {
    const float* src = W + (long)(c * 64 + g * 32 + l31) * K + s * 16 + kg * 8;
    unsigned short o[8];
#pragma unroll
    for (int j = 0; j < 8; ++j) o[j] = f2bf(src[j]);
    uint4 pk;
    pk.x = (unsigned)o[0] | ((unsigned)o[1] << 16);
    pk.y = (unsigned)o[2] | ((unsigned)o[3] << 16);
    pk.z = (unsigned)o[4] | ((unsigned)o[5] << 16);
    pk.w = (unsigned)o[6] | ((unsigned)o[7] << 16);
    *reinterpret_cast<uint4*>(P + ((long)(cs * 2) + g) * 512 + lane * 8) = pk;
  }
}

// ---------------------------------------------------------------- GEMM phase
// acc[mt][g] += A(LDS) @ Wpacked, 32x32x16 bf16, wave tile 64 x (G*32).
// A: m=lane&31, k=(lane>>5)*8+j. B: packed lane-direct.
// D: col=lane&31, row=(reg&3)+8*(reg>>2)+4*(lane>>5).
// Depth-4 rolling B prefetch; k-loop starts at rot (wraps mod S).
template <int S, int G, int ASTRIDE>
__device__ __forceinline__ void gemm_phase(
    f32x16 (&acc)[2][G], const unsigned short* h_s,
    const unsigned short* __restrict__ Pl, int cblk, int gbase,
    int lane, int rot) {
  const int l31 = lane & 31, kg = lane >> 5;
  const unsigned short* bbase =
      Pl + ((long)cblk * S * 2 + gbase) * 512 + lane * 8;
  const unsigned short* abase0 = h_s + l31 * ASTRIDE + kg * 8;
  const unsigned short* abase1 = abase0 + 32 * ASTRIDE;

  bf16x8 b[4][G];
  int kp = rot;
#pragma unroll
  for (int p = 0; p < 4; ++p) {
#pragma unroll
    for (int g = 0; g < G; ++g)
      b[p][g] = *reinterpret_cast<const bf16x8*>(bbase + (kp * 2 + g) * 512);
    ++kp; if (kp == S) kp = 0;
  }
  int kc = rot;
  for (int grp = 0; grp < S / 4; ++grp) {
#pragma unroll
    for (int j = 0; j < 4; ++j) {
      bf16x8 a0 = *reinterpret_cast<const bf16x8*>(abase0 + kc * 16);
      bf16x8 a1 = *reinterpret_cast<const bf16x8*>(abase1 + kc * 16);
#pragma unroll
      for (int g = 0; g < G; ++g) {
        acc[0][g] = __builtin_amdgcn_mfma_f32_32x32x16_bf16(
            a0, b[j][g], acc[0][g], 0, 0, 0);
        acc[1][g] = __builtin_amdgcn_mfma_f32_32x32x16_bf16(
            a1, b[j][g], acc[1][g], 0, 0, 0);
      }
      if (grp < S / 4 - 1) {
#pragma unroll
        for (int g = 0; g < G; ++g)
          b[j][g] =
              *reinterpret_cast<const bf16x8*>(bbase + (kp * 2 + g) * 512);
        ++kp; if (kp == S) kp = 0;
      }
      ++kc; if (kc == S) kc = 0;
    }
  }
}

// --------------------------------------------------- LN+tanh epilogue (L0/L1)
// 32-shape D: col=l31, row=(r&3)+8*(r>>2)+4*h (h=lane>>5), per mt +32.
template <int G>
__device__ __forceinline__ void ln_tanh_epilogue(
    f32x16 (&acc)[2][G], unsigned short* h_s,
    const float* __restrict__ bias, const float* __restrict__ g,
    const float* __restrict__ be, float* rsum_s, float* rsq_s, float2* mr_s,
    float invN, int wavecol0, int lane, int t) {
  const int l31 = lane & 31, h = lane >> 5;
  float bv[G], gv[G], bev[G];
#pragma unroll
  for (int gg = 0; gg < G; ++gg) {
    const int c = wavecol0 + gg * 32 + l31;
    bv[gg] = bias[c]; gv[gg] = g[c]; bev[gg] = be[c];
  }
#pragma unroll
  for (int mt = 0; mt < 2; ++mt) {
#pragma unroll
    for (int r = 0; r < 16; ++r) {
      float s = 0.f, ss = 0.f;
#pragma unroll
      for (int gg = 0; gg < G; ++gg) {
        float v = acc[mt][gg][r] + bv[gg];
        s += v; ss += v * v;
      }
#pragma unroll
      for (int m = 16; m >= 1; m >>= 1) {
        s += __shfl_xor(s, m, 32);
        ss += __shfl_xor(ss, m, 32);
      }
      if (l31 == 0) {
        const int row = mt * 32 + 4 * h + (r & 3) + 8 * (r >> 2);
        atomicAdd(&rsum_s[row], s);
        atomicAdd(&rsq_s[row], ss);
      }
    }
  }
  __syncthreads();
  if (t < 64) {
    float mean = rsum_s[t] * invN;
    float var = rsq_s[t] * invN - mean * mean;
    mr_s[t] = make_float2(mean, 1.0f / sqrtf(var + LN_EPS));
    rsum_s[t] = 0.f; rsq_s[t] = 0.f;   // ready for next layer
  }
  __syncthreads();
#pragma unroll
  for (int mt = 0; mt < 2; ++mt)
#pragma unroll
    for (int r = 0; r < 16; ++r) {
      const int row = mt * 32 + 4 * h + (r & 3) + 8 * (r >> 2);
      const float2 mr = mr_s[row];
#pragma unroll
      for (int gg = 0; gg < G; ++gg) {
        float v = acc[mt][gg][r] + bv[gg];
        float a = fast_tanh((v - mr.x) * mr.y * gv[gg] + bev[gg]);
        h_s[row * 1032 + wavecol0 + gg * 32 + l31] = f2bf(a);
      }
    }
  __syncthreads();
}

// ---------------------------------------------------------------- fused MLP
__global__ __launch_bounds__(1024) void fused_mlp(
    const float* __restrict__ x,
    const float* __restrict__ kc_emb, const float* __restrict__ nl_emb,
    const float* __restrict__ op_w, const float* __restrict__ op_b,
    const float* __restrict__ ic_emb, const float* __restrict__ is_emb,
    const float* __restrict__ ii_emb,
    const unsigned short* __restrict__ W0p, const float* __restrict__ b0,
    const float* __restrict__ g0, const float* __restrict__ be0,
    const unsigned short* __restrict__ W1p, const float* __restrict__ b1,
    const float* __restrict__ g1, const float* __restrict__ be1,
    const unsigned short* __restrict__ W2p, const float* __restrict__ b2,
    const float* __restrict__ g2, const float* __restrict__ be2,
    const float* __restrict__ W3, const float* __restrict__ b3,
    float* __restrict__ out) {
  // One buffer, three lives: F (stride 584, 64x576), h1, h2 (stride 1032).
  __shared__ __align__(16) unsigned short h_s[64 * 1032];  // 132,096 B
  __shared__ float rsum_s[64], rsq_s[64], out_s[64];
  __shared__ float2 mr_s[64];

  const int t = threadIdx.x;
  const int wave = t >> 6, lane = t & 63;
  const int l31 = lane & 31, h = lane >> 5;
  const int bx = blockIdx.x;
  const long rowbase = (long)bx * 64;
  // k-rotation: decorrelate concurrent blocks' weight streams
  const int mix = bx + (bx >> 3);
  const int rot36 = mix % 36;
  const int rot64 = mix & 63;

  if (t < 64) { rsum_s[t] = 0.f; rsq_s[t] = 0.f; out_s[t] = 0.f; }

  // ---- featurize: 64 rows -> h_s, stride 584; 16 waves x 4 rows
#pragma unroll
  for (int rr = 0; rr < 4; ++rr) {
    const int r = rr * 16 + wave;
    const float* xr = x + (rowbase + r) * 323;
    unsigned short* fr = h_s + r * 584;
#pragma unroll
    for (int i = 0; i < 9; ++i) {
      const int f = lane + i * 64;
      float v;
      if (f < 32) {
        v = kc_emb[(int)xr[0] * 32 + f];
      } else if (f < 64) {
        v = nl_emb[(int)xr[1] * 32 + (f - 32)];
      } else if (f < 176) {
        const int j = (f - 64) >> 1, c = (f - 64) & 1;
        v = xr[2 + j] * op_w[j * 2 + c] + op_b[j * 2 + c];
      } else if (f < 178) {
        v = xr[58 + (f - 176)];
      } else if (f < 568) {
        const int gidx = f - 178;
        const int blk = gidx / 26;
        const int r2 = gidx - blk * 26;
        const int base = 60 + 17 * blk;
        if (r2 < 14)      v = xr[base + r2];
        else if (r2 < 18) v = ic_emb[(int)xr[base + 14] * 4 + (r2 - 14)];
        else if (r2 < 22) v = is_emb[(int)xr[base + 15] * 4 + (r2 - 18)];
        else              v = ii_emb[(int)xr[base + 16] * 4 + (r2 - 22)];
      } else {
        v = xr[315 + (f - 568)];
      }
      fr[f] = f2bf(v);
    }
  }
  __syncthreads();

  // ---- layer 0: K=576 (36 k16-steps), N=1024; wave cols = wave*64..+63
  {
    f32x16 acc[2][2] = {};
    gemm_phase<36, 2, 584>(acc, h_s, W0p, wave, 0, lane, rot36);
    ln_tanh_epilogue<2>(acc, h_s, b0, g0, be0, rsum_s, rsq_s, mr_s,
                        1.0f / 1024.f, wave * 64, lane, t);
  }
  // ---- layer 1: K=1024 (64 steps), N=1024
  {
    f32x16 acc[2][2] = {};
    gemm_phase<64, 2, 1032>(acc, h_s, W1p, wave, 0, lane, rot64);
    ln_tanh_epilogue<2>(acc, h_s, b1, g1, be1, rsum_s, rsq_s, mr_s,
                        1.0f / 1024.f, wave * 64, lane, t);
  }
  // ---- layer 2 + final dot: K=1024, N=512; wave cols = wave*32..+31
  {
    f32x16 acc[2][1] = {};
    gemm_phase<64, 1, 1032>(acc, h_s, W2p, wave >> 1, wave & 1, lane, rot64);

    const int c = wave * 32 + l31;
    float bv = b2[c], gv = g2[c], bev = be2[c], wv = W3[c];
#pragma unroll
    for (int mt = 0; mt < 2; ++mt) {
#pragma unroll
      for (int r = 0; r < 16; ++r) {
        float v = acc[mt][0][r] + bv;
        float s = v, ss = v * v;
#pragma unroll
        for (int m = 16; m >= 1; m >>= 1) {
          s += __shfl_xor(s, m, 32);
          ss += __shfl_xor(ss, m, 32);
        }
        if (l31 == 0) {
          const int row = mt * 32 + 4 * h + (r & 3) + 8 * (r >> 2);
          atomicAdd(&rsum_s[row], s);
          atomicAdd(&rsq_s[row], ss);
        }
      }
    }
    __syncthreads();
    if (t < 64) {
      float mean = rsum_s[t] * (1.0f / 512.f);
      float var = rsq_s[t] * (1.0f / 512.f) - mean * mean;
      mr_s[t] = make_float2(mean, 1.0f / sqrtf(var + LN_EPS));
    }
    __syncthreads();
#pragma unroll
    for (int mt = 0; mt < 2; ++mt) {
#pragma unroll
      for (int r = 0; r < 16; ++r) {
        const int row = mt * 32 + 4 * h + (r & 3) + 8 * (r >> 2);
        const float2 mr = mr_s[row];
        float v = acc[mt][0][r] + bv;
        float o = fast_tanh((v - mr.x) * mr.y * gv + bev) * wv;
#pragma unroll
        for (int m = 16; m >= 1; m >>= 1) o += __shfl_xor(o, m, 32);
        if (l31 == 0) atomicAdd(&out_s[row], o);
      }
    }
    __syncthreads();
    if (t < 64) out[rowbase + t] = out_s[t] + b3[0];
  }
}

// ---------------------------------------------------------------- launch
extern "C" void kernel_launch(void* const* d_in, const int* in_sizes, int n_in,
                              void* d_out, int out_size, void* d_ws,
                              size_t ws_size, hipStream_t stream) {
  const float* x      = (const float*)d_in[0];
  const float* kc_emb = (const float*)d_in[1];
  const float* nl_emb = (const float*)d_in[2];
  const float* op_w   = (const float*)d_in[3];
  const float* op_b   = (const float*)d_in[4];
  const float* ic_emb = (const float*)d_in[5];
  const float* is_emb = (const float*)d_in[6];
  const float* ii_emb = (const float*)d_in[7];
  const float* W0  = (const float*)d_in[8];
  const float* b0  = (const float*)d_in[9];
  const float* W1  = (const float*)d_in[10];
  const float* b1  = (const float*)d_in[11];
  const float* W2  = (const float*)d_in[12];
  const float* b2  = (const float*)d_in[13];
  const float* W3  = (const float*)d_in[14];
  const float* b3  = (const float*)d_in[15];
  const float* g0  = (const float*)d_in[16];
  const float* be0 = (const float*)d_in[17];
  const float* g1  = (const float*)d_in[18];
  const float* be1 = (const float*)d_in[19];
  const float* g2  = (const float*)d_in[20];
  const float* be2 = (const float*)d_in[21];

  // ws: W0p @0 (1,179,648 B) | W1p @1,179,648 (2,097,152) | W2p @3,276,800
  // (1,048,576). Total 4,325,376 B.
  char* ws = (char*)d_ws;
  unsigned short* W0p = (unsigned short*)(ws);
  unsigned short* W1p = (unsigned short*)(ws + 1179648LL);
  unsigned short* W2p = (unsigned short*)(ws + 3276800LL);

  // 2112 waves total (576 + 1024 + 512), 4 waves/block
  pack_all<<<dim3(528), dim3(256), 0, stream>>>(W0, W1, W2, W0p, W1p, W2p);
  fused_mlp<<<dim3(1024), dim3(1024), 0, stream>>>(
      x, kc_emb, nl_emb, op_w, op_b, ic_emb, is_emb, ii_emb,
      W0p, b0, g0, be0, W1p, b1, g1, be1, W2p, b2, g2, be2,
      W3, b3, (float*)d_out);
}

// Round 7
// 534.787 us; speedup vs baseline: 1.4351x; 1.4351x over previous
//
#include <hip/hip_runtime.h>
#include <hip/hip_bf16.h>

// Fully-fused MLP: featurize + (GEMM+LN+tanh) x3 + final dot, one kernel.
// R7: revert to R5 16x16x32 structure (R6's 32x32 shape +125us pure stall);
// + h-stride 1040 (8-bank row shift -> epilogue LDS write conflicts ~0;
//   R5's 2.15e7 conflicts were the scalar h-writes, proven by R6's zero);
// + stage x rows in LDS (bf16, index cols pre-truncated) so featurize
//   gathers hit LDS instead of 36 dependent global chains per wave.

typedef __attribute__((ext_vector_type(8))) short bf16x8;   // 8 bf16 = 4 VGPRs
typedef __attribute__((ext_vector_type(4))) float f32x4;    // MFMA accumulator

#define LN_EPS 1e-5f

__device__ __forceinline__ float bf2f(short u) {
  union { unsigned u; float f; } c;
  c.u = ((unsigned)(unsigned short)u) << 16;
  return c.f;
}
// RNE float->bf16
__device__ __forceinline__ unsigned short f2bf(float f) {
  union { float f; unsigned u; } c; c.f = f;
  unsigned u = c.u;
  u += 0x7FFFu + ((u >> 16) & 1u);
  return (unsigned short)(u >> 16);
}
// tanh(x) = 1 - 2/(1+e^{2x}); v_exp_f32 + v_rcp_f32, ~1e-7 rel err.
__device__ __forceinline__ float fast_tanh(float x) {
  float e = __builtin_amdgcn_exp2f(x * 2.8853900817779268f);  // 2*log2(e)
  float r = __builtin_amdgcn_rcpf(e + 1.0f);
  return 1.0f - 2.0f * r;
}

// ------------------------------------------------------------- pack weights
// P[((c*NSTEPS + s)*4 + g)*64 + lane][0..7] = W[c*64 + g*16 + (lane&15)]
//                                              [s*32 + (lane>>4)*8 + j]
// One wave per (c,s); contiguous 1KB per (c,s,g) in GEMM-wave lane order.
__global__ void pack_all(const float* __restrict__ W0,
                         const float* __restrict__ W1,
                         const float* __restrict__ W2,
                         unsigned short* __restrict__ P0,
                         unsigned short* __restrict__ P1,
                         unsigned short* __restrict__ P2) {
  const int wv = blockIdx.x * 4 + (threadIdx.x >> 6);
  const int lane = threadIdx.x & 63;
  const float* W; unsigned short* P; int K, NSTEPS, cs;
  if (wv < 288)      { W = W0; P = P0; K = 576;  NSTEPS = 18; cs = wv; }
  else if (wv < 800) { W = W1; P = P1; K = 1024; NSTEPS = 32; cs = wv - 288; }
  else               { W = W2; P = P2; K = 1024; NSTEPS = 32; cs = wv - 800; }
  const int s = cs % NSTEPS, c = cs / NSTEPS;
  const int quad = lane >> 4, l15 = lane & 15;
#pragma unroll
  for (int g = 0; g < 4; ++g) {
    const float* src = W + (long)(c * 64 + g * 16 + l15) * K + s * 32 + quad * 8;
    unsigned short o[8];
#pragma unroll
    for (int j = 0; j < 8; ++j) o[j] = f2bf(src[j]);
    uint4 pk;
    pk.x = (unsigned)o[0] | ((unsigned)o[1] << 16);
    pk.y = (unsigned)o[2] | ((unsigned)o[3] << 16);
    pk.z = (unsigned)o[4] | ((unsigned)o[5] << 16);
    pk.w = (unsigned)o[6] | ((unsigned)o[7] << 16);
    *reinterpret_cast<uint4*>(P + ((long)(cs * 4 + g) * 64 + lane) * 8) = pk;
  }
}

// ---------------------------------------------------------------- GEMM phase
// acc[mt][nt] += A(LDS rows) @ Wpacked. MFMA 16x16x32 bf16.
// A-frag: m=l15, k=quad*8+j (from h_s). B-frag: packed, lane-direct.
// D: col=l15 (n), row=quad*4+reg (m).
template <int NSTEPS, int NT, int ASTRIDE>
__device__ __forceinline__ void gemm_phase(
    f32x4 (&acc)[4][NT], const unsigned short* h_s,
    const unsigned short* __restrict__ Pl, int cblk, int ntbase,
    int lane, int rot) {
  const int quad = lane >> 4, l15 = lane & 15;
  // step s chunk = 4 groups * 64 lanes * 8 = 2048 elems (4KB); group = 512
  const unsigned short* base =
      Pl + ((long)cblk * NSTEPS * 4 + ntbase) * 512 + lane * 8;

  bf16x8 bcur[NT], bnxt[NT];
  {
    const unsigned short* p = base + rot * 2048;
#pragma unroll
    for (int nt = 0; nt < NT; ++nt)
      bcur[nt] = *reinterpret_cast<const bf16x8*>(p + nt * 512);
  }
#pragma unroll 2
  for (int i = 0; i < NSTEPS; ++i) {
    if (i + 1 < NSTEPS) {
      int sn = i + 1 + rot; if (sn >= NSTEPS) sn -= NSTEPS;
      const unsigned short* p = base + sn * 2048;
#pragma unroll
      for (int nt = 0; nt < NT; ++nt)
        bnxt[nt] = *reinterpret_cast<const bf16x8*>(p + nt * 512);
    }
    int sc = i + rot; if (sc >= NSTEPS) sc -= NSTEPS;
    bf16x8 a[4];
#pragma unroll
    for (int mt = 0; mt < 4; ++mt)
      a[mt] = *reinterpret_cast<const bf16x8*>(
          h_s + (mt * 16 + l15) * ASTRIDE + sc * 32 + quad * 8);
#pragma unroll
    for (int mt = 0; mt < 4; ++mt)
#pragma unroll
      for (int nt = 0; nt < NT; ++nt)
        acc[mt][nt] = __builtin_amdgcn_mfma_f32_16x16x32_bf16(
            a[mt], bcur[nt], acc[mt][nt], 0, 0, 0);
#pragma unroll
    for (int nt = 0; nt < NT; ++nt) bcur[nt] = bnxt[nt];
  }
}

// --------------------------------------------------- LN+tanh epilogue (L0/L1)
template <int NT>
__device__ __forceinline__ void ln_tanh_epilogue(
    f32x4 (&acc)[4][NT], unsigned short* h_s,
    const float* __restrict__ bias, const float* __restrict__ g,
    const float* __restrict__ be, float* rsum_s, float* rsq_s, float2* mr_s,
    float invN, int wavecol0, int quad, int l15, int t) {
  float bv[NT], gv[NT], bev[NT];
#pragma unroll
  for (int nt = 0; nt < NT; ++nt) {
    const int c = wavecol0 + nt * 16 + l15;
    bv[nt] = bias[c]; gv[nt] = g[c]; bev[nt] = be[c];
  }
#pragma unroll
  for (int mt = 0; mt < 4; ++mt) {
#pragma unroll
    for (int reg = 0; reg < 4; ++reg) {
      float s = 0.f, ss = 0.f;
#pragma unroll
      for (int nt = 0; nt < NT; ++nt) {
        float v = acc[mt][nt][reg] + bv[nt];
        s += v; ss += v * v;
      }
#pragma unroll
      for (int m = 8; m >= 1; m >>= 1) {
        s += __shfl_xor(s, m, 16);
        ss += __shfl_xor(ss, m, 16);
      }
      if (l15 == 0) {
        atomicAdd(&rsum_s[mt * 16 + quad * 4 + reg], s);
        atomicAdd(&rsq_s[mt * 16 + quad * 4 + reg], ss);
      }
    }
  }
  __syncthreads();
  if (t < 64) {
    float mean = rsum_s[t] * invN;
    float var = rsq_s[t] * invN - mean * mean;
    mr_s[t] = make_float2(mean, 1.0f / sqrtf(var + LN_EPS));
    rsum_s[t] = 0.f; rsq_s[t] = 0.f;   // ready for next layer
  }
  __syncthreads();
#pragma unroll
  for (int mt = 0; mt < 4; ++mt)
#pragma unroll
    for (int reg = 0; reg < 4; ++reg) {
      const int row = mt * 16 + quad * 4 + reg;
      const float2 mr = mr_s[row];
#pragma unroll
      for (int nt = 0; nt < NT; ++nt) {
        float v = acc[mt][nt][reg] + bv[nt];
        float a = fast_tanh((v - mr.x) * mr.y * gv[nt] + bev[nt]);
        h_s[row * 1040 + wavecol0 + nt * 16 + l15] = f2bf(a);
      }
    }
  __syncthreads();
}

// ---------------------------------------------------------------- fused MLP
__global__ __launch_bounds__(1024) void fused_mlp(
    const float* __restrict__ x,
    const float* __restrict__ kc_emb, const float* __restrict__ nl_emb,
    const float* __restrict__ op_w, const float* __restrict__ op_b,
    const float* __restrict__ ic_emb, const float* __restrict__ is_emb,
    const float* __restrict__ ii_emb,
    const unsigned short* __restrict__ W0p, const float* __restrict__ b0,
    const float* __restrict__ g0, const float* __restrict__ be0,
    const unsigned short* __restrict__ W1p, const float* __restrict__ b1,
    const float* __restrict__ g1, const float* __restrict__ be1,
    const unsigned short* __restrict__ W2p, const float* __restrict__ b2,
    const float* __restrict__ g2, const float* __restrict__ be2,
    const float* __restrict__ W3, const float* __restrict__ b3,
    float* __restrict__ out) {
  // One buffer, several lives: x-stage (offset 37376, stride 324) + F
  // (stride 584, rows 0..63) during featurize; then h1/h2 (stride 1040).
  __shared__ __align__(16) unsigned short h_s[64 * 1040];  // 133,120 B
  __shared__ float rsum_s[64], rsq_s[64], out_s[64];
  __shared__ float2 mr_s[64];

  const int t = threadIdx.x;
  const int wave = t >> 6, lane = t & 63, quad = lane >> 4, l15 = lane & 15;
  const int bx = blockIdx.x;
  const long rowbase = (long)bx * 64;
  // k-rotation: decorrelate concurrent blocks' weight streams
  const int mix = bx + (bx >> 3);
  const int rot18 = mix % 18;
  const int rot32 = mix & 31;

  if (t < 64) { rsum_s[t] = 0.f; rsq_s[t] = 0.f; out_s[t] = 0.f; }

  // ---- stage x -> LDS bf16 (coalesced); index cols pre-truncated so
  // embedding lookups stay exact (small ints are exact in bf16).
  unsigned short* xs = h_s + 37376;   // after F region (64*584)
#pragma unroll
  for (int rr = 0; rr < 4; ++rr) {
    const int r = rr * 16 + wave;
    const float* xr = x + (rowbase + r) * 323;
    unsigned short* xsr = xs + r * 324;
#pragma unroll
    for (int i = 0; i < 6; ++i) {
      const int c = lane + i * 64;
      if (c < 323) {
        float v = xr[c];
        const int cb = c - 60;
        const bool idx = (c < 2) || (c >= 60 && c < 315 && (cb % 17) >= 14);
        if (idx) v = (float)(int)v;
        xsr[c] = f2bf(v);
      }
    }
  }
  __syncthreads();

  // ---- featurize: 64 rows -> F (stride 584), reading x from LDS
#pragma unroll
  for (int rr = 0; rr < 4; ++rr) {
    const int r = rr * 16 + wave;
    const unsigned short* xsr = xs + r * 324;
    unsigned short* fr = h_s + r * 584;
#pragma unroll
    for (int i = 0; i < 9; ++i) {
      const int f = lane + i * 64;
      float v;
      if (f < 32) {
        v = kc_emb[(int)bf2f(xsr[0]) * 32 + f];
      } else if (f < 64) {
        v = nl_emb[(int)bf2f(xsr[1]) * 32 + (f - 32)];
      } else if (f < 176) {
        const int j = (f - 64) >> 1, c = (f - 64) & 1;
        v = bf2f(xsr[2 + j]) * op_w[j * 2 + c] + op_b[j * 2 + c];
      } else if (f < 178) {
        v = bf2f(xsr[58 + (f - 176)]);
      } else if (f < 568) {
        const int gidx = f - 178;
        const int blk = gidx / 26;
        const int r2 = gidx - blk * 26;
        const int base = 60 + 17 * blk;
        if (r2 < 14)      v = bf2f(xsr[base + r2]);
        else if (r2 < 18) v = ic_emb[(int)bf2f(xsr[base + 14]) * 4 + (r2 - 14)];
        else if (r2 < 22) v = is_emb[(int)bf2f(xsr[base + 15]) * 4 + (r2 - 18)];
        else              v = ii_emb[(int)bf2f(xsr[base + 16]) * 4 + (r2 - 22)];
      } else {
        v = bf2f(xsr[315 + (f - 568)]);
      }
      fr[f] = f2bf(v);
    }
  }
  __syncthreads();

  const f32x4 fz = {0.f, 0.f, 0.f, 0.f};

  // ---- layer 0: K=576 (18 steps), N=1024; wave cols = wave*64..+63
  {
    f32x4 acc[4][4];
#pragma unroll
    for (int mt = 0; mt < 4; ++mt)
#pragma unroll
      for (int nt = 0; nt < 4; ++nt) acc[mt][nt] = fz;
    gemm_phase<18, 4, 584>(acc, h_s, W0p, wave, 0, lane, rot18);
    ln_tanh_epilogue<4>(acc, h_s, b0, g0, be0, rsum_s, rsq_s, mr_s,
                        1.0f / 1024.f, wave * 64, quad, l15, t);
  }
  // ---- layer 1: K=1024 (32 steps), N=1024
  {
    f32x4 acc[4][4];
#pragma unroll
    for (int mt = 0; mt < 4; ++mt)
#pragma unroll
      for (int nt = 0; nt < 4; ++nt) acc[mt][nt] = fz;
    gemm_phase<32, 4, 1040>(acc, h_s, W1p, wave, 0, lane, rot32);
    ln_tanh_epilogue<4>(acc, h_s, b1, g1, be1, rsum_s, rsq_s, mr_s,
                        1.0f / 1024.f, wave * 64, quad, l15, t);
  }
  // ---- layer 2 + final dot: K=1024, N=512; wave cols = wave*32..+31
  {
    f32x4 acc[4][2];
#pragma unroll
    for (int mt = 0; mt < 4; ++mt)
#pragma unroll
      for (int nt = 0; nt < 2; ++nt) acc[mt][nt] = fz;
    gemm_phase<32, 2, 1040>(acc, h_s, W2p, wave >> 1, (wave & 1) * 2, lane,
                            rot32);

    float bv[2], gv[2], bev[2], wv[2];
#pragma unroll
    for (int nt = 0; nt < 2; ++nt) {
      const int c = wave * 32 + nt * 16 + l15;
      bv[nt] = b2[c]; gv[nt] = g2[c]; bev[nt] = be2[c]; wv[nt] = W3[c];
    }
#pragma unroll
    for (int mt = 0; mt < 4; ++mt) {
#pragma unroll
      for (int reg = 0; reg < 4; ++reg) {
        float s = 0.f, ss = 0.f;
#pragma unroll
        for (int nt = 0; nt < 2; ++nt) {
          float v = acc[mt][nt][reg] + bv[nt];
          s += v; ss += v * v;
        }
#pragma unroll
        for (int m = 8; m >= 1; m >>= 1) {
          s += __shfl_xor(s, m, 16);
          ss += __shfl_xor(ss, m, 16);
        }
        if (l15 == 0) {
          atomicAdd(&rsum_s[mt * 16 + quad * 4 + reg], s);
          atomicAdd(&rsq_s[mt * 16 + quad * 4 + reg], ss);
        }
      }
    }
    __syncthreads();
    if (t < 64) {
      float mean = rsum_s[t] * (1.0f / 512.f);
      float var = rsq_s[t] * (1.0f / 512.f) - mean * mean;
      mr_s[t] = make_float2(mean, 1.0f / sqrtf(var + LN_EPS));
    }
    __syncthreads();
#pragma unroll
    for (int mt = 0; mt < 4; ++mt) {
#pragma unroll
      for (int reg = 0; reg < 4; ++reg) {
        const int row = mt * 16 + quad * 4 + reg;
        const float2 mr = mr_s[row];
        float o = 0.f;
#pragma unroll
        for (int nt = 0; nt < 2; ++nt) {
          float v = acc[mt][nt][reg] + bv[nt];
          float a = fast_tanh((v - mr.x) * mr.y * gv[nt] + bev[nt]);
          o += a * wv[nt];
        }
#pragma unroll
        for (int m = 8; m >= 1; m >>= 1) o += __shfl_xor(o, m, 16);
        if (l15 == 0) atomicAdd(&out_s[row], o);
      }
    }
    __syncthreads();
    if (t < 64) out[rowbase + t] = out_s[t] + b3[0];
  }
}

// ---------------------------------------------------------------- launch
extern "C" void kernel_launch(void* const* d_in, const int* in_sizes, int n_in,
                              void* d_out, int out_size, void* d_ws,
                              size_t ws_size, hipStream_t stream) {
  const float* x      = (const float*)d_in[0];
  const float* kc_emb = (const float*)d_in[1];
  const float* nl_emb = (const float*)d_in[2];
  const float* op_w   = (const float*)d_in[3];
  const float* op_b   = (const float*)d_in[4];
  const float* ic_emb = (const float*)d_in[5];
  const float* is_emb = (const float*)d_in[6];
  const float* ii_emb = (const float*)d_in[7];
  const float* W0  = (const float*)d_in[8];
  const float* b0  = (const float*)d_in[9];
  const float* W1  = (const float*)d_in[10];
  const float* b1  = (const float*)d_in[11];
  const float* W2  = (const float*)d_in[12];
  const float* b2  = (const float*)d_in[13];
  const float* W3  = (const float*)d_in[14];
  const float* b3  = (const float*)d_in[15];
  const float* g0  = (const float*)d_in[16];
  const float* be0 = (const float*)d_in[17];
  const float* g1  = (const float*)d_in[18];
  const float* be1 = (const float*)d_in[19];
  const float* g2  = (const float*)d_in[20];
  const float* be2 = (const float*)d_in[21];

  // ws: W0p @0 (1,179,648 B) | W1p @1,179,648 (2,097,152) | W2p @3,276,800
  // (1,048,576). Total 4,325,376 B.
  char* ws = (char*)d_ws;
  unsigned short* W0p = (unsigned short*)(ws);
  unsigned short* W1p = (unsigned short*)(ws + 1179648LL);
  unsigned short* W2p = (unsigned short*)(ws + 3276800LL);

  // 1056 waves total (288 + 512 + 256), 4 waves/block
  pack_all<<<dim3(264), dim3(256), 0, stream>>>(W0, W1, W2, W0p, W1p, W2p);
  fused_mlp<<<dim3(1024), dim3(1024), 0, stream>>>(
      x, kc_emb, nl_emb, op_w, op_b, ic_emb, is_emb, ii_emb,
      W0p, b0, g0, be0, W1p, b1, g1, be1, W2p, b2, g2, be2,
      W3, b3, (float*)d_out);
}